// Round 1
// baseline (785.859 us; speedup 1.0000x reference)
//
#include <hip/hip_runtime.h>
#include <stdint.h>

typedef unsigned short u16;
typedef __attribute__((ext_vector_type(8))) unsigned short u16x8;
typedef __attribute__((ext_vector_type(8))) __bf16 bf16x8;
typedef __attribute__((ext_vector_type(4))) float f32x4;

#define NNODES 32768
#define NEDGES 131072
#define DDIM 512
#define QK4 2048   // 4*DDIM
#define MM 4096
#define UU 8

__device__ __forceinline__ u16 f2bf(float f) {
    unsigned u = __builtin_bit_cast(unsigned, f);
    u += 0x7FFFu + ((u >> 16) & 1u);
    return (u16)(u >> 16);
}
__device__ __forceinline__ float bf2f(u16 h) {
    return __builtin_bit_cast(float, (unsigned)h << 16);
}

__device__ __forceinline__ void load_lds16(const void* g, void* l) {
    __builtin_amdgcn_global_load_lds((__attribute__((address_space(1))) unsigned int*)(void*)g,
                                     (__attribute__((address_space(3))) unsigned int*)l, 16, 0, 0);
}

// ---------------- utility ----------------
__global__ void k_zero(unsigned int* p, int n) {
    int i = blockIdx.x * 256 + threadIdx.x;
    if (i < n) p[i] = 0u;
}

// ---------------- input prep ----------------
__global__ void k_build_x0(const float* __restrict__ mc, const int* __restrict__ mask,
                           const float* __restrict__ sp, const float* __restrict__ cm,
                           const float* __restrict__ at, float* __restrict__ x0) {
    int node = blockIdx.x * 256 + threadIdx.x;
    if (node >= NNODES) return;
    int m = node >> 3, u = node & 7;
    float* o = x0 + (size_t)node * 6;
    o[0] = mc[m * 2];
    o[1] = mc[m * 2 + 1];
    o[2] = (float)mask[m];
    o[3] = sp[u];
    o[4] = cm[u * MM + m];
    o[5] = at[u * MM + m];
}

__global__ void k_w0cat(const float* __restrict__ Wq0, const float* __restrict__ Wk0,
                        const float* __restrict__ Wv0, const float* __restrict__ Ws0,
                        float* __restrict__ W0cat) {
    int i = blockIdx.x * 256 + threadIdx.x;
    if (i >= 6 * QK4) return;
    int k = i / QK4, n = i % QK4;
    int t = n >> 9, nn = n & 511;
    const float* p = (t == 0) ? Wq0 : (t == 1) ? Wk0 : (t == 2) ? Wv0 : Ws0;
    W0cat[i] = p[k * DDIM + nn];
}

__global__ void k_bcat(const float* __restrict__ bq0, const float* __restrict__ bk0,
                       const float* __restrict__ bv0, const float* __restrict__ bs0,
                       const float* __restrict__ bq, const float* __restrict__ bk,
                       const float* __restrict__ bv, const float* __restrict__ bs,
                       float* __restrict__ b0cat, float* __restrict__ bcat) {
    int i = blockIdx.x * 256 + threadIdx.x;  // 0..8191
    if (i >= 4 * QK4) return;
    int n = i & (QK4 - 1);
    int l = i >> 11;
    int t = n >> 9, nn = n & 511;
    if (l == 0) {
        const float* p = (t == 0) ? bq0 : (t == 1) ? bk0 : (t == 2) ? bv0 : bs0;
        b0cat[n] = p[nn];
    } else {
        const float* p = (t == 0) ? bq : (t == 1) ? bk : (t == 2) ? bv : bs;
        bcat[(size_t)(l - 1) * QK4 + n] = p[(l - 1) * DDIM + nn];
    }
}

// transpose [512][512] fp32 matrices into Wt[layer][2048][512] bf16 ([n][k])
__global__ void k_wt(const float* __restrict__ Wq, const float* __restrict__ Wk,
                     const float* __restrict__ Wv, const float* __restrict__ Ws,
                     u16* __restrict__ Wt) {
    __shared__ float tile[32][33];
    int q = blockIdx.z;
    int l = q >> 2, t = q & 3;
    const float* src = ((t == 0) ? Wq : (t == 1) ? Wk : (t == 2) ? Wv : Ws) + (size_t)l * DDIM * DDIM;
    int k0 = blockIdx.x * 32, n0 = blockIdx.y * 32;
    int tx = threadIdx.x, ty = threadIdx.y;
#pragma unroll
    for (int r = 0; r < 4; r++) tile[ty + 8 * r][tx] = src[(size_t)(k0 + ty + 8 * r) * DDIM + n0 + tx];
    __syncthreads();
    u16* dst = Wt + (size_t)l * QK4 * DDIM + (size_t)t * DDIM * DDIM;
#pragma unroll
    for (int r = 0; r < 4; r++) {
        int n = n0 + ty + 8 * r;
        dst[(size_t)n * DDIM + k0 + tx] = f2bf(tile[tx][ty + 8 * r]);
    }
}

// ---------------- CSR build ----------------
__global__ void k_count(const int* __restrict__ dst, int* __restrict__ deg) {
    int e = blockIdx.x * 256 + threadIdx.x;
    if (e < NEDGES) atomicAdd(&deg[dst[e]], 1);
}

__global__ __launch_bounds__(1024) void k_scan(const int* __restrict__ deg, int* __restrict__ offs,
                                               int* __restrict__ cursor) {
    __shared__ int sums[1024];
    int t = threadIdx.x;
    int base = t * 32;
    int local[32];
    int s = 0;
#pragma unroll
    for (int i = 0; i < 32; i++) { local[i] = s; s += deg[base + i]; }
    sums[t] = s;
    __syncthreads();
    for (int d = 1; d < 1024; d <<= 1) {
        int v = (t >= d) ? sums[t - d] : 0;
        __syncthreads();
        sums[t] += v;
        __syncthreads();
    }
    int excl = (t == 0) ? 0 : sums[t - 1];
#pragma unroll
    for (int i = 0; i < 32; i++) {
        int o = excl + local[i];
        offs[base + i] = o;
        cursor[base + i] = o;
    }
    if (t == 1023) offs[NNODES] = sums[1023];
}

__global__ void k_scatter(const int* __restrict__ src, const int* __restrict__ dst,
                          int* __restrict__ cursor, int* __restrict__ ssrc) {
    int e = blockIdx.x * 256 + threadIdx.x;
    if (e < NEDGES) {
        int pos = atomicAdd(&cursor[dst[e]], 1);
        ssrc[pos] = src[e];
    }
}

// ---------------- layer 0 GEMM (K=6) ----------------
__global__ __launch_bounds__(256) void k_gemm0(const float* __restrict__ x0, const float* __restrict__ W0cat,
                                               const float* __restrict__ b0cat, u16* __restrict__ QKVS) {
    int node = blockIdx.x;
    int t = threadIdx.x;
    float xv[6];
#pragma unroll
    for (int k = 0; k < 6; k++) xv[k] = x0[(size_t)node * 6 + k];
    int n0 = t * 8;
    u16x8 o;
#pragma unroll
    for (int j = 0; j < 8; j++) {
        int n = n0 + j;
        float s = b0cat[n];
#pragma unroll
        for (int k = 0; k < 6; k++) s += xv[k] * W0cat[k * QK4 + n];
        o[j] = f2bf(s);
    }
    *(u16x8*)(QKVS + (size_t)node * QK4 + n0) = o;
}

// ---------------- main MFMA GEMM: X[32768,512]bf16 @ Wt[2048,512]bf16^T -> QKVS bf16 ----------------
__global__ __launch_bounds__(256, 3) void k_gemm(const u16* __restrict__ X, const u16* __restrict__ Wt,
                                                 const float* __restrict__ bcat, u16* __restrict__ C) {
    __shared__ __align__(16) u16 As[128 * 64];
    __shared__ __align__(16) u16 Bs[128 * 64];
    const int tid = threadIdx.x;
    const int lane = tid & 63;
    const int w = tid >> 6;
    const int wm = w & 1, wn = w >> 1;
    const size_t arow0 = (size_t)blockIdx.x * 128;
    const size_t brow0 = (size_t)blockIdx.y * 128;

    f32x4 acc[4][4];
#pragma unroll
    for (int i = 0; i < 4; i++)
#pragma unroll
        for (int j = 0; j < 4; j++) acc[i][j] = (f32x4){0.f, 0.f, 0.f, 0.f};

    const int la = lane & 7;
    const int quad = lane >> 4;
    const int lm = lane & 15;

    for (int kt = 0; kt < 8; ++kt) {
        const int k0 = kt * 64;
#pragma unroll
        for (int t = 0; t < 4; ++t) {
            int idx = (w * 4 + t) * 64 + lane;
            int m = idx >> 3;
            int c = la ^ (m & 7);
            const u16* ga = X + (arow0 + m) * DDIM + (k0 + c * 8);
            const u16* gb = Wt + (brow0 + m) * DDIM + (k0 + c * 8);
            load_lds16(ga, &As[(size_t)((w * 4 + t) * 64) * 8]);
            load_lds16(gb, &Bs[(size_t)((w * 4 + t) * 64) * 8]);
        }
        __syncthreads();
#pragma unroll
        for (int kk = 0; kk < 2; ++kk) {
            bf16x8 af[4], bfg[4];
            int c = kk * 4 + quad;
#pragma unroll
            for (int i = 0; i < 4; ++i) {
                int m = wm * 64 + i * 16 + lm;
                int slot = m * 8 + (c ^ (m & 7));
                af[i] = *(const bf16x8*)&As[(size_t)slot * 8];
            }
#pragma unroll
            for (int j = 0; j < 4; ++j) {
                int n = wn * 64 + j * 16 + lm;
                int slot = n * 8 + (c ^ (n & 7));
                bfg[j] = *(const bf16x8*)&Bs[(size_t)slot * 8];
            }
#pragma unroll
            for (int i = 0; i < 4; ++i)
#pragma unroll
                for (int j = 0; j < 4; ++j)
                    acc[i][j] = __builtin_amdgcn_mfma_f32_16x16x32_bf16(af[i], bfg[j], acc[i][j], 0, 0, 0);
        }
        __syncthreads();
    }
    // epilogue: C[row][col], col=lane&15, row=quad*4+reg
#pragma unroll
    for (int j = 0; j < 4; ++j) {
        size_t gcol = brow0 + wn * 64 + j * 16 + lm;
        float bias = bcat[gcol];
#pragma unroll
        for (int i = 0; i < 4; ++i) {
            size_t grow = arow0 + wm * 64 + i * 16 + quad * 4;
#pragma unroll
            for (int r = 0; r < 4; ++r) {
                C[(grow + r) * QK4 + gcol] = f2bf(acc[i][j][r] + bias);
            }
        }
    }
}

// ---------------- attention: one wave per dst node ----------------
__global__ __launch_bounds__(256) void k_attn(const u16* __restrict__ QKVS, const int* __restrict__ offs,
                                              const int* __restrict__ ssrc, u16* __restrict__ Xout) {
    const int lane = threadIdx.x & 63;
    const int node = blockIdx.x * 4 + (threadIdx.x >> 6);
    const int c0 = lane * 8;
    const u16x8 qv = *(const u16x8*)(QKVS + (size_t)node * QK4 + c0);
    float qf[8];
#pragma unroll
    for (int j = 0; j < 8; j++) qf[j] = bf2f(qv[j]);
    float m = -INFINITY, l = 0.f;
    float acc[8];
#pragma unroll
    for (int j = 0; j < 8; j++) acc[j] = 0.f;
    const int e0 = offs[node], e1 = offs[node + 1];
    for (int e = e0; e < e1; ++e) {
        int s = ssrc[e];
        const u16x8 kv = *(const u16x8*)(QKVS + (size_t)s * QK4 + 512 + c0);
        const u16x8 vv = *(const u16x8*)(QKVS + (size_t)s * QK4 + 1024 + c0);
        float d = 0.f;
#pragma unroll
        for (int j = 0; j < 8; j++) d += qf[j] * bf2f(kv[j]);
        d += __shfl_xor(d, 1, 64);
        d += __shfl_xor(d, 2, 64);
        d += __shfl_xor(d, 4, 64);
        float a = d * 0.125f;
        float nm = fmaxf(m, a);
        float corr = __expf(m - nm);
        float p = __expf(a - nm);
        l = l * corr + p;
#pragma unroll
        for (int j = 0; j < 8; j++) acc[j] = acc[j] * corr + p * bf2f(vv[j]);
        m = nm;
    }
    float inv = 1.0f / (l + 1e-16f);
    const u16x8 sv = *(const u16x8*)(QKVS + (size_t)node * QK4 + 1536 + c0);
    u16x8 o;
#pragma unroll
    for (int j = 0; j < 8; j++) {
        float r = acc[j] * inv + bf2f(sv[j]);
        o[j] = f2bf(fmaxf(r, 0.f));
    }
    *(u16x8*)(Xout + (size_t)node * DDIM + c0) = o;
}

// ---------------- pooling ----------------
__global__ __launch_bounds__(256) void k_pool(const u16* __restrict__ X, float* __restrict__ pooled) {
    int t = threadIdx.x;
    int nd0 = blockIdx.x * 512;
    float s0 = 0.f, s1 = 0.f;
    for (int nd = nd0; nd < nd0 + 512; ++nd) {
        s0 += bf2f(X[(size_t)nd * DDIM + t]);
        s1 += bf2f(X[(size_t)nd * DDIM + 256 + t]);
    }
    atomicAdd(&pooled[t], s0);
    atomicAdd(&pooled[t + 256], s1);
}

// ---------------- heads: emb + hidden layers + critic ----------------
__global__ __launch_bounds__(1024) void k_heads(const float* __restrict__ pooled, const float* __restrict__ fcW,
                                                const float* __restrict__ fcb, const float* __restrict__ ui,
                                                const float* __restrict__ sp, const float* __restrict__ aW1,
                                                const float* __restrict__ ab1, const float* __restrict__ cW1,
                                                const float* __restrict__ cb1, const float* __restrict__ cW2,
                                                const float* __restrict__ cb2, float* __restrict__ hidden_a,
                                                float* __restrict__ out) {
    __shared__ float spool[512];
    __shared__ float semb[64];
    __shared__ float shc[8][128];
    int t = threadIdx.x;
    if (t < 512) spool[t] = pooled[t] * (1.0f / 32768.0f);
    __syncthreads();
    if (t < 64) {
        float s = fcb[t];
        for (int k = 0; k < 512; k++) s += spool[k] * fcW[k * 64 + t];
        semb[t] = s;
    }
    __syncthreads();
    int u = t >> 7, j = t & 127;
    float u0 = ui[u * 2], u1 = ui[u * 2 + 1], uspd = sp[u];
    float ha = ab1[j] + u0 * aW1[j] + u1 * aW1[128 + j] + uspd * aW1[66 * 128 + j];
    float hc = cb1[j] + u0 * cW1[j] + u1 * cW1[128 + j] + uspd * cW1[66 * 128 + j];
    for (int k = 0; k < 64; k++) {
        float e = semb[k];
        ha += e * aW1[(2 + k) * 128 + j];
        hc += e * cW1[(2 + k) * 128 + j];
    }
    ha = fmaxf(ha, 0.f);
    hc = fmaxf(hc, 0.f);
    hidden_a[u * 128 + j] = ha;
    shc[u][j] = hc;
    __syncthreads();
    if (t < 8) {
        float s = cb2[0];
        for (int k = 0; k < 128; k++) s += shc[t][k] * cW2[k];
        out[NNODES + t] = s;  // 8*4096 = 32768 probs first
    }
}

// ---------------- actor logits + softmax ----------------
__global__ __launch_bounds__(1024) void k_actor(const float* __restrict__ hidden_a, const float* __restrict__ aW2,
                                                const float* __restrict__ ab2, float* __restrict__ out) {
    __shared__ float h[128];
    __shared__ float red[1024];
    int u = blockIdx.x, t = threadIdx.x;
    if (t < 128) h[t] = hidden_a[u * 128 + t];
    __syncthreads();
    float lg[4];
#pragma unroll
    for (int p = 0; p < 4; p++) {
        int mcol = t + p * 1024;
        float s = ab2[mcol];
        for (int k = 0; k < 128; k++) s += h[k] * aW2[(size_t)k * MM + mcol];
        lg[p] = s;
    }
    float mx = fmaxf(fmaxf(lg[0], lg[1]), fmaxf(lg[2], lg[3]));
    red[t] = mx;
    __syncthreads();
    for (int s2 = 512; s2 > 0; s2 >>= 1) {
        if (t < s2) red[t] = fmaxf(red[t], red[t + s2]);
        __syncthreads();
    }
    mx = red[0];
    __syncthreads();
    float e[4], sum = 0.f;
#pragma unroll
    for (int p = 0; p < 4; p++) {
        e[p] = __expf(lg[p] - mx);
        sum += e[p];
    }
    red[t] = sum;
    __syncthreads();
    for (int s2 = 512; s2 > 0; s2 >>= 1) {
        if (t < s2) red[t] += red[t + s2];
        __syncthreads();
    }
    float inv = 1.0f / red[0];
#pragma unroll
    for (int p = 0; p < 4; p++) out[(size_t)u * MM + t + p * 1024] = e[p] * inv;
}

extern "C" void kernel_launch(void* const* d_in, const int* in_sizes, int n_in,
                              void* d_out, int out_size, void* d_ws, size_t ws_size,
                              hipStream_t stream) {
    const float* mc   = (const float*)d_in[0];
    const float* ui   = (const float*)d_in[1];
    const float* sp   = (const float*)d_in[2];
    const float* cm   = (const float*)d_in[3];
    const float* at   = (const float*)d_in[4];
    const int*   eidx = (const int*)d_in[5];
    const int*   mask = (const int*)d_in[7];
    const float* Wq0 = (const float*)d_in[8];
    const float* bq0 = (const float*)d_in[9];
    const float* Wk0 = (const float*)d_in[10];
    const float* bk0 = (const float*)d_in[11];
    const float* Wv0 = (const float*)d_in[12];
    const float* bv0 = (const float*)d_in[13];
    const float* Ws0 = (const float*)d_in[14];
    const float* bs0 = (const float*)d_in[15];
    const float* Wq = (const float*)d_in[16];
    const float* bq = (const float*)d_in[17];
    const float* Wk = (const float*)d_in[18];
    const float* bk = (const float*)d_in[19];
    const float* Wv = (const float*)d_in[20];
    const float* bv = (const float*)d_in[21];
    const float* Ws = (const float*)d_in[22];
    const float* bs = (const float*)d_in[23];
    const float* fcW = (const float*)d_in[24];
    const float* fcb = (const float*)d_in[25];
    const float* aW1 = (const float*)d_in[26];
    const float* ab1 = (const float*)d_in[27];
    const float* aW2 = (const float*)d_in[28];
    const float* ab2 = (const float*)d_in[29];
    const float* cW1 = (const float*)d_in[30];
    const float* cb1 = (const float*)d_in[31];
    const float* cW2 = (const float*)d_in[32];
    const float* cb2 = (const float*)d_in[33];
    float* out = (float*)d_out;

    const int* esrc = eidx;
    const int* edst = eidx + NEDGES;

    char* ws = (char*)d_ws;
    size_t off = 0;
    auto alloc = [&](size_t bytes) -> void* {
        void* p = ws + off;
        off += (bytes + 255) & ~(size_t)255;
        return p;
    };
    u16*   QKVS  = (u16*)alloc((size_t)NNODES * QK4 * 2);    // 128 MB
    u16*   X     = (u16*)alloc((size_t)NNODES * DDIM * 2);   // 32 MB
    u16*   Wt    = (u16*)alloc((size_t)3 * QK4 * DDIM * 2);  // 6 MB
    float* W0cat = (float*)alloc((size_t)6 * QK4 * 4);
    float* b0cat = (float*)alloc((size_t)QK4 * 4);
    float* bcat  = (float*)alloc((size_t)3 * QK4 * 4);
    float* x0    = (float*)alloc((size_t)NNODES * 6 * 4);
    int*   deg   = (int*)alloc((size_t)NNODES * 4);
    int*   offs  = (int*)alloc((size_t)(NNODES + 1) * 4);
    int*   cursor= (int*)alloc((size_t)NNODES * 4);
    int*   ssrc  = (int*)alloc((size_t)NEDGES * 4);
    float* pooled= (float*)alloc((size_t)512 * 4);
    float* hidden_a = (float*)alloc((size_t)UU * 128 * 4);
    (void)ws_size; (void)in_sizes; (void)n_in; (void)out_size;

    // prep
    k_zero<<<(NNODES + 255) / 256, 256, 0, stream>>>((unsigned int*)deg, NNODES);
    k_zero<<<2, 256, 0, stream>>>((unsigned int*)pooled, 512);
    k_build_x0<<<NNODES / 256, 256, 0, stream>>>(mc, mask, sp, cm, at, x0);
    k_w0cat<<<(6 * QK4 + 255) / 256, 256, 0, stream>>>(Wq0, Wk0, Wv0, Ws0, W0cat);
    k_bcat<<<(4 * QK4 + 255) / 256, 256, 0, stream>>>(bq0, bk0, bv0, bs0, bq, bk, bv, bs, b0cat, bcat);
    {
        dim3 g(16, 16, 12), b(32, 8);
        k_wt<<<g, b, 0, stream>>>(Wq, Wk, Wv, Ws, Wt);
    }
    // CSR
    k_count<<<NEDGES / 256, 256, 0, stream>>>(edst, deg);
    k_scan<<<1, 1024, 0, stream>>>(deg, offs, cursor);
    k_scatter<<<NEDGES / 256, 256, 0, stream>>>(esrc, edst, cursor, ssrc);

    // layer 0
    k_gemm0<<<NNODES, 256, 0, stream>>>(x0, W0cat, b0cat, QKVS);
    k_attn<<<NNODES / 4, 256, 0, stream>>>(QKVS, offs, ssrc, X);

    // layers 1..3
    for (int l = 0; l < 3; ++l) {
        dim3 g(NNODES / 128, QK4 / 128);
        k_gemm<<<g, 256, 0, stream>>>(X, Wt + (size_t)l * QK4 * DDIM, bcat + (size_t)l * QK4, QKVS);
        k_attn<<<NNODES / 4, 256, 0, stream>>>(QKVS, offs, ssrc, X);
    }

    // pool + heads
    k_pool<<<64, 256, 0, stream>>>(X, pooled);
    k_heads<<<1, 1024, 0, stream>>>(pooled, fcW, fcb, ui, sp, aW1, ab1, cW1, cb1, cW2, cb2, hidden_a, out);
    k_actor<<<UU, 1024, 0, stream>>>(hidden_a, aW2, ab2, out);
}

// Round 2
// 747.673 us; speedup vs baseline: 1.0511x; 1.0511x over previous
//
#include <hip/hip_runtime.h>
#include <stdint.h>

typedef unsigned short u16;
typedef __attribute__((ext_vector_type(8))) unsigned short u16x8;
typedef __attribute__((ext_vector_type(8))) __bf16 bf16x8;
typedef __attribute__((ext_vector_type(4))) float f32x4;

#define NNODES 32768
#define NEDGES 131072
#define DDIM 512
#define QK4 2048   // 4*DDIM
#define MM 4096
#define UU 8

__device__ __forceinline__ u16 f2bf(float f) {
    unsigned u = __builtin_bit_cast(unsigned, f);
    u += 0x7FFFu + ((u >> 16) & 1u);
    return (u16)(u >> 16);
}
__device__ __forceinline__ float bf2f(u16 h) {
    return __builtin_bit_cast(float, (unsigned)h << 16);
}

__device__ __forceinline__ void load_lds16(const void* g, void* l) {
    __builtin_amdgcn_global_load_lds((__attribute__((address_space(1))) unsigned int*)(void*)g,
                                     (__attribute__((address_space(3))) unsigned int*)l, 16, 0, 0);
}

// ---------------- utility ----------------
__global__ void k_zero(unsigned int* p, int n) {
    int i = blockIdx.x * 256 + threadIdx.x;
    if (i < n) p[i] = 0u;
}

// ---------------- input prep ----------------
__global__ void k_build_x0(const float* __restrict__ mc, const int* __restrict__ mask,
                           const float* __restrict__ sp, const float* __restrict__ cm,
                           const float* __restrict__ at, float* __restrict__ x0) {
    int node = blockIdx.x * 256 + threadIdx.x;
    if (node >= NNODES) return;
    int m = node >> 3, u = node & 7;
    float* o = x0 + (size_t)node * 6;
    o[0] = mc[m * 2];
    o[1] = mc[m * 2 + 1];
    o[2] = (float)mask[m];
    o[3] = sp[u];
    o[4] = cm[u * MM + m];
    o[5] = at[u * MM + m];
}

__global__ void k_w0cat(const float* __restrict__ Wq0, const float* __restrict__ Wk0,
                        const float* __restrict__ Wv0, const float* __restrict__ Ws0,
                        float* __restrict__ W0cat) {
    int i = blockIdx.x * 256 + threadIdx.x;
    if (i >= 6 * QK4) return;
    int k = i / QK4, n = i % QK4;
    int t = n >> 9, nn = n & 511;
    const float* p = (t == 0) ? Wq0 : (t == 1) ? Wk0 : (t == 2) ? Wv0 : Ws0;
    W0cat[i] = p[k * DDIM + nn];
}

__global__ void k_bcat(const float* __restrict__ bq0, const float* __restrict__ bk0,
                       const float* __restrict__ bv0, const float* __restrict__ bs0,
                       const float* __restrict__ bq, const float* __restrict__ bk,
                       const float* __restrict__ bv, const float* __restrict__ bs,
                       float* __restrict__ b0cat, float* __restrict__ bcat) {
    int i = blockIdx.x * 256 + threadIdx.x;  // 0..8191
    if (i >= 4 * QK4) return;
    int n = i & (QK4 - 1);
    int l = i >> 11;
    int t = n >> 9, nn = n & 511;
    if (l == 0) {
        const float* p = (t == 0) ? bq0 : (t == 1) ? bk0 : (t == 2) ? bv0 : bs0;
        b0cat[n] = p[nn];
    } else {
        const float* p = (t == 0) ? bq : (t == 1) ? bk : (t == 2) ? bv : bs;
        bcat[(size_t)(l - 1) * QK4 + n] = p[(l - 1) * DDIM + nn];
    }
}

// transpose [512][512] fp32 matrices into Wt[layer][2048][512] bf16 ([n][k])
__global__ void k_wt(const float* __restrict__ Wq, const float* __restrict__ Wk,
                     const float* __restrict__ Wv, const float* __restrict__ Ws,
                     u16* __restrict__ Wt) {
    __shared__ float tile[32][33];
    int q = blockIdx.z;
    int l = q >> 2, t = q & 3;
    const float* src = ((t == 0) ? Wq : (t == 1) ? Wk : (t == 2) ? Wv : Ws) + (size_t)l * DDIM * DDIM;
    int k0 = blockIdx.x * 32, n0 = blockIdx.y * 32;
    int tx = threadIdx.x, ty = threadIdx.y;
#pragma unroll
    for (int r = 0; r < 4; r++) tile[ty + 8 * r][tx] = src[(size_t)(k0 + ty + 8 * r) * DDIM + n0 + tx];
    __syncthreads();
    u16* dst = Wt + (size_t)l * QK4 * DDIM + (size_t)t * DDIM * DDIM;
#pragma unroll
    for (int r = 0; r < 4; r++) {
        int n = n0 + ty + 8 * r;
        dst[(size_t)n * DDIM + k0 + tx] = f2bf(tile[tx][ty + 8 * r]);
    }
}

// ---------------- CSR build ----------------
__global__ void k_count(const int* __restrict__ dst, int* __restrict__ deg) {
    int e = blockIdx.x * 256 + threadIdx.x;
    if (e < NEDGES) atomicAdd(&deg[dst[e]], 1);
}

__global__ __launch_bounds__(1024) void k_scan(const int* __restrict__ deg, int* __restrict__ offs,
                                               int* __restrict__ cursor) {
    __shared__ int sums[1024];
    int t = threadIdx.x;
    int base = t * 32;
    int local[32];
    int s = 0;
#pragma unroll
    for (int i = 0; i < 32; i++) { local[i] = s; s += deg[base + i]; }
    sums[t] = s;
    __syncthreads();
    for (int d = 1; d < 1024; d <<= 1) {
        int v = (t >= d) ? sums[t - d] : 0;
        __syncthreads();
        sums[t] += v;
        __syncthreads();
    }
    int excl = (t == 0) ? 0 : sums[t - 1];
#pragma unroll
    for (int i = 0; i < 32; i++) {
        int o = excl + local[i];
        offs[base + i] = o;
        cursor[base + i] = o;
    }
    if (t == 1023) offs[NNODES] = sums[1023];
}

__global__ void k_scatter(const int* __restrict__ src, const int* __restrict__ dst,
                          int* __restrict__ cursor, int* __restrict__ ssrc) {
    int e = blockIdx.x * 256 + threadIdx.x;
    if (e < NEDGES) {
        int pos = atomicAdd(&cursor[dst[e]], 1);
        ssrc[pos] = src[e];
    }
}

// ---------------- layer 0 GEMM (K=6) ----------------
__global__ __launch_bounds__(256) void k_gemm0(const float* __restrict__ x0, const float* __restrict__ W0cat,
                                               const float* __restrict__ b0cat, u16* __restrict__ QKVS) {
    int node = blockIdx.x;
    int t = threadIdx.x;
    float xv[6];
#pragma unroll
    for (int k = 0; k < 6; k++) xv[k] = x0[(size_t)node * 6 + k];
    int n0 = t * 8;
    u16x8 o;
#pragma unroll
    for (int j = 0; j < 8; j++) {
        int n = n0 + j;
        float s = b0cat[n];
#pragma unroll
        for (int k = 0; k < 6; k++) s += xv[k] * W0cat[k * QK4 + n];
        o[j] = f2bf(s);
    }
    *(u16x8*)(QKVS + (size_t)node * QK4 + n0) = o;
}

// ---------------- main MFMA GEMM: X[32768,512]bf16 @ Wt[2048,512]bf16^T -> QKVS bf16 ----------------
// grid: (QK4/128, NNODES/128) -> N-tiles fastest so concurrent blocks share one A tile (L2 reuse)
__global__ __launch_bounds__(256, 3) void k_gemm(const u16* __restrict__ X, const u16* __restrict__ Wt,
                                                 const float* __restrict__ bcat, u16* __restrict__ C) {
    __shared__ __align__(16) u16 smem[2 * 128 * 64];  // 32 KB: As | Bs, reused as epilogue staging
    u16* As = smem;
    u16* Bs = smem + 128 * 64;
    const int tid = threadIdx.x;
    const int lane = tid & 63;
    const int w = tid >> 6;
    const int wm = w & 1, wn = w >> 1;
    const size_t brow0 = (size_t)blockIdx.x * 128;
    const size_t arow0 = (size_t)blockIdx.y * 128;

    f32x4 acc[4][4];
#pragma unroll
    for (int i = 0; i < 4; i++)
#pragma unroll
        for (int j = 0; j < 4; j++) acc[i][j] = (f32x4){0.f, 0.f, 0.f, 0.f};

    const int la = lane & 7;
    const int quad = lane >> 4;
    const int lm = lane & 15;

    for (int kt = 0; kt < 8; ++kt) {
        const int k0 = kt * 64;
#pragma unroll
        for (int t = 0; t < 4; ++t) {
            int idx = (w * 4 + t) * 64 + lane;
            int m = idx >> 3;
            int c = la ^ (m & 7);
            const u16* ga = X + (arow0 + m) * DDIM + (k0 + c * 8);
            const u16* gb = Wt + (brow0 + m) * DDIM + (k0 + c * 8);
            load_lds16(ga, &As[(size_t)((w * 4 + t) * 64) * 8]);
            load_lds16(gb, &Bs[(size_t)((w * 4 + t) * 64) * 8]);
        }
        __syncthreads();
#pragma unroll
        for (int kk = 0; kk < 2; ++kk) {
            bf16x8 af[4], bfg[4];
            int c = kk * 4 + quad;
#pragma unroll
            for (int i = 0; i < 4; ++i) {
                int m = wm * 64 + i * 16 + lm;
                int slot = m * 8 + (c ^ (m & 7));
                af[i] = *(const bf16x8*)&As[(size_t)slot * 8];
            }
#pragma unroll
            for (int j = 0; j < 4; ++j) {
                int n = wn * 64 + j * 16 + lm;
                int slot = n * 8 + (c ^ (n & 7));
                bfg[j] = *(const bf16x8*)&Bs[(size_t)slot * 8];
            }
#pragma unroll
            for (int i = 0; i < 4; ++i)
#pragma unroll
                for (int j = 0; j < 4; ++j)
                    acc[i][j] = __builtin_amdgcn_mfma_f32_16x16x32_bf16(af[i], bfg[j], acc[i][j], 0, 0, 0);
        }
        __syncthreads();
    }

    // epilogue: stage wave's 64x64 subtile through LDS -> coalesced 16B/lane global stores.
    // acc layout: C[row][col], col=lane&15, row=quad*4+reg (within each i*16/j*16 cell)
    float biasv[4];
#pragma unroll
    for (int j = 0; j < 4; ++j) biasv[j] = bcat[brow0 + wn * 64 + j * 16 + lm];

    u16* stg = smem;  // [4 waves][32 rows][72 u16]
    const int chunk = lane & 7;
    const int rrow = lane >> 3;
#pragma unroll
    for (int p = 0; p < 2; ++p) {
        __syncthreads();
#pragma unroll
        for (int ii = 0; ii < 2; ++ii) {
            int i = p * 2 + ii;
#pragma unroll
            for (int j = 0; j < 4; ++j) {
#pragma unroll
                for (int r = 0; r < 4; ++r) {
                    int lr = ii * 16 + quad * 4 + r;
                    int lc = j * 16 + lm;
                    stg[(size_t)(w * 32 + lr) * 72 + lc] = f2bf(acc[i][j][r] + biasv[j]);
                }
            }
        }
        __syncthreads();
#pragma unroll
        for (int it = 0; it < 4; ++it) {
            int row = it * 8 + rrow;
            u16x8 v = *(const u16x8*)&stg[(size_t)(w * 32 + row) * 72 + chunk * 8];
            *(u16x8*)&C[(arow0 + wm * 64 + p * 32 + row) * QK4 + brow0 + wn * 64 + chunk * 8] = v;
        }
    }
}

// ---------------- attention: one wave per dst node ----------------
__global__ __launch_bounds__(256) void k_attn(const u16* __restrict__ QKVS, const int* __restrict__ offs,
                                              const int* __restrict__ ssrc, u16* __restrict__ Xout) {
    const int lane = threadIdx.x & 63;
    const int node = blockIdx.x * 4 + (threadIdx.x >> 6);
    const int c0 = lane * 8;
    const u16x8 qv = *(const u16x8*)(QKVS + (size_t)node * QK4 + c0);
    float qf[8];
#pragma unroll
    for (int j = 0; j < 8; j++) qf[j] = bf2f(qv[j]);
    float m = -INFINITY, l = 0.f;
    float acc[8];
#pragma unroll
    for (int j = 0; j < 8; j++) acc[j] = 0.f;
    const int e0 = offs[node], e1 = offs[node + 1];
    for (int e = e0; e < e1; ++e) {
        int s = ssrc[e];
        const u16x8 kv = *(const u16x8*)(QKVS + (size_t)s * QK4 + 512 + c0);
        const u16x8 vv = *(const u16x8*)(QKVS + (size_t)s * QK4 + 1024 + c0);
        float d = 0.f;
#pragma unroll
        for (int j = 0; j < 8; j++) d += qf[j] * bf2f(kv[j]);
        d += __shfl_xor(d, 1, 64);
        d += __shfl_xor(d, 2, 64);
        d += __shfl_xor(d, 4, 64);
        float a = d * 0.125f;
        float nm = fmaxf(m, a);
        float corr = __expf(m - nm);
        float p = __expf(a - nm);
        l = l * corr + p;
#pragma unroll
        for (int j = 0; j < 8; j++) acc[j] = acc[j] * corr + p * bf2f(vv[j]);
        m = nm;
    }
    float inv = 1.0f / (l + 1e-16f);
    const u16x8 sv = *(const u16x8*)(QKVS + (size_t)node * QK4 + 1536 + c0);
    u16x8 o;
#pragma unroll
    for (int j = 0; j < 8; j++) {
        float r = acc[j] * inv + bf2f(sv[j]);
        o[j] = f2bf(fmaxf(r, 0.f));
    }
    *(u16x8*)(Xout + (size_t)node * DDIM + c0) = o;
}

// ---------------- pooling ----------------
__global__ __launch_bounds__(256) void k_pool(const u16* __restrict__ X, float* __restrict__ pooled) {
    int t = threadIdx.x;
    int nd0 = blockIdx.x * 512;
    float s0 = 0.f, s1 = 0.f;
    for (int nd = nd0; nd < nd0 + 512; ++nd) {
        s0 += bf2f(X[(size_t)nd * DDIM + t]);
        s1 += bf2f(X[(size_t)nd * DDIM + 256 + t]);
    }
    atomicAdd(&pooled[t], s0);
    atomicAdd(&pooled[t + 256], s1);
}

// ---------------- heads: emb + hidden layers + critic ----------------
__global__ __launch_bounds__(1024) void k_heads(const float* __restrict__ pooled, const float* __restrict__ fcW,
                                                const float* __restrict__ fcb, const float* __restrict__ ui,
                                                const float* __restrict__ sp, const float* __restrict__ aW1,
                                                const float* __restrict__ ab1, const float* __restrict__ cW1,
                                                const float* __restrict__ cb1, const float* __restrict__ cW2,
                                                const float* __restrict__ cb2, float* __restrict__ hidden_a,
                                                float* __restrict__ out) {
    __shared__ float spool[512];
    __shared__ float semb[64];
    __shared__ float shc[8][128];
    int t = threadIdx.x;
    if (t < 512) spool[t] = pooled[t] * (1.0f / 32768.0f);
    __syncthreads();
    if (t < 64) {
        float s = fcb[t];
        for (int k = 0; k < 512; k++) s += spool[k] * fcW[k * 64 + t];
        semb[t] = s;
    }
    __syncthreads();
    int u = t >> 7, j = t & 127;
    float u0 = ui[u * 2], u1 = ui[u * 2 + 1], uspd = sp[u];
    float ha = ab1[j] + u0 * aW1[j] + u1 * aW1[128 + j] + uspd * aW1[66 * 128 + j];
    float hc = cb1[j] + u0 * cW1[j] + u1 * cW1[128 + j] + uspd * cW1[66 * 128 + j];
    for (int k = 0; k < 64; k++) {
        float e = semb[k];
        ha += e * aW1[(2 + k) * 128 + j];
        hc += e * cW1[(2 + k) * 128 + j];
    }
    ha = fmaxf(ha, 0.f);
    hc = fmaxf(hc, 0.f);
    hidden_a[u * 128 + j] = ha;
    shc[u][j] = hc;
    __syncthreads();
    if (t < 8) {
        float s = cb2[0];
        for (int k = 0; k < 128; k++) s += shc[t][k] * cW2[k];
        out[NNODES + t] = s;  // 8*4096 = 32768 probs first
    }
}

// ---------------- actor logits + softmax ----------------
__global__ __launch_bounds__(1024) void k_actor(const float* __restrict__ hidden_a, const float* __restrict__ aW2,
                                                const float* __restrict__ ab2, float* __restrict__ out) {
    __shared__ float h[128];
    __shared__ float red[1024];
    int u = blockIdx.x, t = threadIdx.x;
    if (t < 128) h[t] = hidden_a[u * 128 + t];
    __syncthreads();
    float lg[4];
#pragma unroll
    for (int p = 0; p < 4; p++) {
        int mcol = t + p * 1024;
        float s = ab2[mcol];
        for (int k = 0; k < 128; k++) s += h[k] * aW2[(size_t)k * MM + mcol];
        lg[p] = s;
    }
    float mx = fmaxf(fmaxf(lg[0], lg[1]), fmaxf(lg[2], lg[3]));
    red[t] = mx;
    __syncthreads();
    for (int s2 = 512; s2 > 0; s2 >>= 1) {
        if (t < s2) red[t] = fmaxf(red[t], red[t + s2]);
        __syncthreads();
    }
    mx = red[0];
    __syncthreads();
    float e[4], sum = 0.f;
#pragma unroll
    for (int p = 0; p < 4; p++) {
        e[p] = __expf(lg[p] - mx);
        sum += e[p];
    }
    red[t] = sum;
    __syncthreads();
    for (int s2 = 512; s2 > 0; s2 >>= 1) {
        if (t < s2) red[t] += red[t + s2];
        __syncthreads();
    }
    float inv = 1.0f / red[0];
#pragma unroll
    for (int p = 0; p < 4; p++) out[(size_t)u * MM + t + p * 1024] = e[p] * inv;
}

extern "C" void kernel_launch(void* const* d_in, const int* in_sizes, int n_in,
                              void* d_out, int out_size, void* d_ws, size_t ws_size,
                              hipStream_t stream) {
    const float* mc   = (const float*)d_in[0];
    const float* ui   = (const float*)d_in[1];
    const float* sp   = (const float*)d_in[2];
    const float* cm   = (const float*)d_in[3];
    const float* at   = (const float*)d_in[4];
    const int*   eidx = (const int*)d_in[5];
    const int*   mask = (const int*)d_in[7];
    const float* Wq0 = (const float*)d_in[8];
    const float* bq0 = (const float*)d_in[9];
    const float* Wk0 = (const float*)d_in[10];
    const float* bk0 = (const float*)d_in[11];
    const float* Wv0 = (const float*)d_in[12];
    const float* bv0 = (const float*)d_in[13];
    const float* Ws0 = (const float*)d_in[14];
    const float* bs0 = (const float*)d_in[15];
    const float* Wq = (const float*)d_in[16];
    const float* bq = (const float*)d_in[17];
    const float* Wk = (const float*)d_in[18];
    const float* bk = (const float*)d_in[19];
    const float* Wv = (const float*)d_in[20];
    const float* bv = (const float*)d_in[21];
    const float* Ws = (const float*)d_in[22];
    const float* bs = (const float*)d_in[23];
    const float* fcW = (const float*)d_in[24];
    const float* fcb = (const float*)d_in[25];
    const float* aW1 = (const float*)d_in[26];
    const float* ab1 = (const float*)d_in[27];
    const float* aW2 = (const float*)d_in[28];
    const float* ab2 = (const float*)d_in[29];
    const float* cW1 = (const float*)d_in[30];
    const float* cb1 = (const float*)d_in[31];
    const float* cW2 = (const float*)d_in[32];
    const float* cb2 = (const float*)d_in[33];
    float* out = (float*)d_out;

    const int* esrc = eidx;
    const int* edst = eidx + NEDGES;

    char* ws = (char*)d_ws;
    size_t off = 0;
    auto alloc = [&](size_t bytes) -> void* {
        void* p = ws + off;
        off += (bytes + 255) & ~(size_t)255;
        return p;
    };
    u16*   QKVS  = (u16*)alloc((size_t)NNODES * QK4 * 2);    // 128 MB
    u16*   X     = (u16*)alloc((size_t)NNODES * DDIM * 2);   // 32 MB
    u16*   Wt    = (u16*)alloc((size_t)3 * QK4 * DDIM * 2);  // 6 MB
    float* W0cat = (float*)alloc((size_t)6 * QK4 * 4);
    float* b0cat = (float*)alloc((size_t)QK4 * 4);
    float* bcat  = (float*)alloc((size_t)3 * QK4 * 4);
    float* x0    = (float*)alloc((size_t)NNODES * 6 * 4);
    int*   deg   = (int*)alloc((size_t)NNODES * 4);
    int*   offs  = (int*)alloc((size_t)(NNODES + 1) * 4);
    int*   cursor= (int*)alloc((size_t)NNODES * 4);
    int*   ssrc  = (int*)alloc((size_t)NEDGES * 4);
    float* pooled= (float*)alloc((size_t)512 * 4);
    float* hidden_a = (float*)alloc((size_t)UU * 128 * 4);
    (void)ws_size; (void)in_sizes; (void)n_in; (void)out_size;

    // prep
    k_zero<<<(NNODES + 255) / 256, 256, 0, stream>>>((unsigned int*)deg, NNODES);
    k_zero<<<2, 256, 0, stream>>>((unsigned int*)pooled, 512);
    k_build_x0<<<NNODES / 256, 256, 0, stream>>>(mc, mask, sp, cm, at, x0);
    k_w0cat<<<(6 * QK4 + 255) / 256, 256, 0, stream>>>(Wq0, Wk0, Wv0, Ws0, W0cat);
    k_bcat<<<(4 * QK4 + 255) / 256, 256, 0, stream>>>(bq0, bk0, bv0, bs0, bq, bk, bv, bs, b0cat, bcat);
    {
        dim3 g(16, 16, 12), b(32, 8);
        k_wt<<<g, b, 0, stream>>>(Wq, Wk, Wv, Ws, Wt);
    }
    // CSR
    k_count<<<NEDGES / 256, 256, 0, stream>>>(edst, deg);
    k_scan<<<1, 1024, 0, stream>>>(deg, offs, cursor);
    k_scatter<<<NEDGES / 256, 256, 0, stream>>>(esrc, edst, cursor, ssrc);

    // layer 0
    k_gemm0<<<NNODES, 256, 0, stream>>>(x0, W0cat, b0cat, QKVS);
    k_attn<<<NNODES / 4, 256, 0, stream>>>(QKVS, offs, ssrc, X);

    // layers 1..3
    for (int l = 0; l < 3; ++l) {
        dim3 g(QK4 / 128, NNODES / 128);  // N-tiles fastest: concurrent blocks share A tile
        k_gemm<<<g, 256, 0, stream>>>(X, Wt + (size_t)l * QK4 * DDIM, bcat + (size_t)l * QK4, QKVS);
        k_attn<<<NNODES / 4, 256, 0, stream>>>(QKVS, offs, ssrc, X);
    }

    // pool + heads
    k_pool<<<64, 256, 0, stream>>>(X, pooled);
    k_heads<<<1, 1024, 0, stream>>>(pooled, fcW, fcb, ui, sp, aW1, ab1, cW1, cb1, cW2, cb2, hidden_a, out);
    k_actor<<<UU, 1024, 0, stream>>>(hidden_a, aW2, ab2, out);
}

// Round 3
// 713.006 us; speedup vs baseline: 1.1022x; 1.0486x over previous
//
#include <hip/hip_runtime.h>
#include <stdint.h>

typedef unsigned short u16;
typedef __attribute__((ext_vector_type(8))) unsigned short u16x8;
typedef __attribute__((ext_vector_type(8))) __bf16 bf16x8;
typedef __attribute__((ext_vector_type(4))) float f32x4;

#define NNODES 32768
#define NEDGES 131072
#define DDIM 512
#define QK4 2048   // 4*DDIM
#define MM 4096
#define UU 8

__device__ __forceinline__ u16 f2bf(float f) {
    unsigned u = __builtin_bit_cast(unsigned, f);
    u += 0x7FFFu + ((u >> 16) & 1u);
    return (u16)(u >> 16);
}
__device__ __forceinline__ float bf2f(u16 h) {
    return __builtin_bit_cast(float, (unsigned)h << 16);
}

__device__ __forceinline__ void load_lds16(const void* g, void* l) {
    __builtin_amdgcn_global_load_lds((__attribute__((address_space(1))) unsigned int*)(void*)g,
                                     (__attribute__((address_space(3))) unsigned int*)l, 16, 0, 0);
}

// ---------------- utility ----------------
__global__ void k_zero(unsigned int* p, int n) {
    int i = blockIdx.x * 256 + threadIdx.x;
    if (i < n) p[i] = 0u;
}

// ---------------- input prep ----------------
__global__ void k_build_x0(const float* __restrict__ mc, const int* __restrict__ mask,
                           const float* __restrict__ sp, const float* __restrict__ cm,
                           const float* __restrict__ at, float* __restrict__ x0) {
    int node = blockIdx.x * 256 + threadIdx.x;
    if (node >= NNODES) return;
    int m = node >> 3, u = node & 7;
    float* o = x0 + (size_t)node * 6;
    o[0] = mc[m * 2];
    o[1] = mc[m * 2 + 1];
    o[2] = (float)mask[m];
    o[3] = sp[u];
    o[4] = cm[u * MM + m];
    o[5] = at[u * MM + m];
}

__global__ void k_w0cat(const float* __restrict__ Wq0, const float* __restrict__ Wk0,
                        const float* __restrict__ Wv0, const float* __restrict__ Ws0,
                        float* __restrict__ W0cat) {
    int i = blockIdx.x * 256 + threadIdx.x;
    if (i >= 6 * QK4) return;
    int k = i / QK4, n = i % QK4;
    int t = n >> 9, nn = n & 511;
    const float* p = (t == 0) ? Wq0 : (t == 1) ? Wk0 : (t == 2) ? Wv0 : Ws0;
    W0cat[i] = p[k * DDIM + nn];
}

__global__ void k_bcat(const float* __restrict__ bq0, const float* __restrict__ bk0,
                       const float* __restrict__ bv0, const float* __restrict__ bs0,
                       const float* __restrict__ bq, const float* __restrict__ bk,
                       const float* __restrict__ bv, const float* __restrict__ bs,
                       float* __restrict__ b0cat, float* __restrict__ bcat) {
    int i = blockIdx.x * 256 + threadIdx.x;  // 0..8191
    if (i >= 4 * QK4) return;
    int n = i & (QK4 - 1);
    int l = i >> 11;
    int t = n >> 9, nn = n & 511;
    if (l == 0) {
        const float* p = (t == 0) ? bq0 : (t == 1) ? bk0 : (t == 2) ? bv0 : bs0;
        b0cat[n] = p[nn];
    } else {
        const float* p = (t == 0) ? bq : (t == 1) ? bk : (t == 2) ? bv : bs;
        bcat[(size_t)(l - 1) * QK4 + n] = p[(l - 1) * DDIM + nn];
    }
}

// transpose [512][512] fp32 matrices into Wt[layer][2048][512] bf16 ([n][k])
__global__ void k_wt(const float* __restrict__ Wq, const float* __restrict__ Wk,
                     const float* __restrict__ Wv, const float* __restrict__ Ws,
                     u16* __restrict__ Wt) {
    __shared__ float tile[32][33];
    int q = blockIdx.z;
    int l = q >> 2, t = q & 3;
    const float* src = ((t == 0) ? Wq : (t == 1) ? Wk : (t == 2) ? Wv : Ws) + (size_t)l * DDIM * DDIM;
    int k0 = blockIdx.x * 32, n0 = blockIdx.y * 32;
    int tx = threadIdx.x, ty = threadIdx.y;
#pragma unroll
    for (int r = 0; r < 4; r++) tile[ty + 8 * r][tx] = src[(size_t)(k0 + ty + 8 * r) * DDIM + n0 + tx];
    __syncthreads();
    u16* dst = Wt + (size_t)l * QK4 * DDIM + (size_t)t * DDIM * DDIM;
#pragma unroll
    for (int r = 0; r < 4; r++) {
        int n = n0 + ty + 8 * r;
        dst[(size_t)n * DDIM + k0 + tx] = f2bf(tile[tx][ty + 8 * r]);
    }
}

// ---------------- CSR build ----------------
__global__ void k_count(const int* __restrict__ dst, int* __restrict__ deg) {
    int e = blockIdx.x * 256 + threadIdx.x;
    if (e < NEDGES) atomicAdd(&deg[dst[e]], 1);
}

__global__ __launch_bounds__(1024) void k_scan(const int* __restrict__ deg, int* __restrict__ offs,
                                               int* __restrict__ cursor) {
    __shared__ int sums[1024];
    int t = threadIdx.x;
    int base = t * 32;
    int local[32];
    int s = 0;
#pragma unroll
    for (int i = 0; i < 32; i++) { local[i] = s; s += deg[base + i]; }
    sums[t] = s;
    __syncthreads();
    for (int d = 1; d < 1024; d <<= 1) {
        int v = (t >= d) ? sums[t - d] : 0;
        __syncthreads();
        sums[t] += v;
        __syncthreads();
    }
    int excl = (t == 0) ? 0 : sums[t - 1];
#pragma unroll
    for (int i = 0; i < 32; i++) {
        int o = excl + local[i];
        offs[base + i] = o;
        cursor[base + i] = o;
    }
    if (t == 1023) offs[NNODES] = sums[1023];
}

__global__ void k_scatter(const int* __restrict__ src, const int* __restrict__ dst,
                          int* __restrict__ cursor, int* __restrict__ ssrc) {
    int e = blockIdx.x * 256 + threadIdx.x;
    if (e < NEDGES) {
        int pos = atomicAdd(&cursor[dst[e]], 1);
        ssrc[pos] = src[e];
    }
}

// ---------------- layer 0 GEMM (K=6) ----------------
__global__ __launch_bounds__(256) void k_gemm0(const float* __restrict__ x0, const float* __restrict__ W0cat,
                                               const float* __restrict__ b0cat, u16* __restrict__ QKVS) {
    int node = blockIdx.x;
    int t = threadIdx.x;
    float xv[6];
#pragma unroll
    for (int k = 0; k < 6; k++) xv[k] = x0[(size_t)node * 6 + k];
    int n0 = t * 8;
    u16x8 o;
#pragma unroll
    for (int j = 0; j < 8; j++) {
        int n = n0 + j;
        float s = b0cat[n];
#pragma unroll
        for (int k = 0; k < 6; k++) s += xv[k] * W0cat[k * QK4 + n];
        o[j] = f2bf(s);
    }
    *(u16x8*)(QKVS + (size_t)node * QK4 + n0) = o;
}

// ---------------- main MFMA GEMM: X[32768,512]bf16 @ Wt[2048,512]bf16^T -> QKVS bf16 ----------------
// 1-D grid, XCD-aware mapping: blocks dispatch round-robin over 8 XCDs (bid&7);
// each XCD owns a contiguous band of 32 A-row-tiles and sweeps all 16 N-tiles,
// so an A tile is fetched into exactly one XCD's L2 and reused by 16 blocks.
__global__ __launch_bounds__(256, 4) void k_gemm(const u16* __restrict__ X, const u16* __restrict__ Wt,
                                                 const float* __restrict__ bcat, u16* __restrict__ C) {
    __shared__ __align__(16) u16 smem[2 * 128 * 64];  // 32 KB: As | Bs, reused as epilogue staging
    u16* As = smem;
    u16* Bs = smem + 128 * 64;
    const int tid = threadIdx.x;
    const int lane = tid & 63;
    const int w = tid >> 6;
    const int wm = w & 1, wn = w >> 1;
    const int bid = blockIdx.x;
    const int xcd = bid & 7;
    const int s = bid >> 3;               // 0..511 within-XCD sequence
    const size_t arow0 = (size_t)(xcd * 32 + (s >> 4)) * 128;  // 32 row-tiles per XCD
    const size_t brow0 = (size_t)(s & 15) * 128;               // 16 N-tiles, consecutive in-XCD

    f32x4 acc[4][4];
#pragma unroll
    for (int i = 0; i < 4; i++)
#pragma unroll
        for (int j = 0; j < 4; j++) acc[i][j] = (f32x4){0.f, 0.f, 0.f, 0.f};

    const int la = lane & 7;
    const int quad = lane >> 4;
    const int lm = lane & 15;

    for (int kt = 0; kt < 8; ++kt) {
        const int k0 = kt * 64;
#pragma unroll
        for (int t = 0; t < 4; ++t) {
            int idx = (w * 4 + t) * 64 + lane;
            int m = idx >> 3;
            int c = la ^ (m & 7);
            const u16* ga = X + (arow0 + m) * DDIM + (k0 + c * 8);
            const u16* gb = Wt + (brow0 + m) * DDIM + (k0 + c * 8);
            load_lds16(ga, &As[(size_t)((w * 4 + t) * 64) * 8]);
            load_lds16(gb, &Bs[(size_t)((w * 4 + t) * 64) * 8]);
        }
        __syncthreads();
#pragma unroll
        for (int kk = 0; kk < 2; ++kk) {
            bf16x8 af[4], bfg[4];
            int c = kk * 4 + quad;
#pragma unroll
            for (int i = 0; i < 4; ++i) {
                int m = wm * 64 + i * 16 + lm;
                int slot = m * 8 + (c ^ (m & 7));
                af[i] = *(const bf16x8*)&As[(size_t)slot * 8];
            }
#pragma unroll
            for (int j = 0; j < 4; ++j) {
                int n = wn * 64 + j * 16 + lm;
                int slot = n * 8 + (c ^ (n & 7));
                bfg[j] = *(const bf16x8*)&Bs[(size_t)slot * 8];
            }
#pragma unroll
            for (int i = 0; i < 4; ++i)
#pragma unroll
                for (int j = 0; j < 4; ++j)
                    acc[i][j] = __builtin_amdgcn_mfma_f32_16x16x32_bf16(af[i], bfg[j], acc[i][j], 0, 0, 0);
        }
        __syncthreads();
    }

    // epilogue: stage wave's 64x64 subtile through LDS -> coalesced 16B/lane global stores.
    // acc layout: C[row][col], col=lane&15, row=quad*4+reg (within each i*16/j*16 cell)
    float biasv[4];
#pragma unroll
    for (int j = 0; j < 4; ++j) biasv[j] = bcat[brow0 + wn * 64 + j * 16 + lm];

    u16* stg = smem;  // [4 waves][32 rows][72 u16]
    const int chunk = lane & 7;
    const int rrow = lane >> 3;
#pragma unroll
    for (int p = 0; p < 2; ++p) {
        __syncthreads();
#pragma unroll
        for (int ii = 0; ii < 2; ++ii) {
            int i = p * 2 + ii;
#pragma unroll
            for (int j = 0; j < 4; ++j) {
#pragma unroll
                for (int r = 0; r < 4; ++r) {
                    int lr = ii * 16 + quad * 4 + r;
                    int lc = j * 16 + lm;
                    stg[(size_t)(w * 32 + lr) * 72 + lc] = f2bf(acc[i][j][r] + biasv[j]);
                }
            }
        }
        __syncthreads();
#pragma unroll
        for (int it = 0; it < 4; ++it) {
            int row = it * 8 + rrow;
            u16x8 v = *(const u16x8*)&stg[(size_t)(w * 32 + row) * 72 + chunk * 8];
            *(u16x8*)&C[(arow0 + wm * 64 + p * 32 + row) * QK4 + brow0 + wn * 64 + chunk * 8] = v;
        }
    }
}

// ---------------- attention: one wave per dst node ----------------
__global__ __launch_bounds__(256) void k_attn(const u16* __restrict__ QKVS, const int* __restrict__ offs,
                                              const int* __restrict__ ssrc, u16* __restrict__ Xout) {
    const int lane = threadIdx.x & 63;
    const int node = blockIdx.x * 4 + (threadIdx.x >> 6);
    const int c0 = lane * 8;
    const u16x8 qv = *(const u16x8*)(QKVS + (size_t)node * QK4 + c0);
    float qf[8];
#pragma unroll
    for (int j = 0; j < 8; j++) qf[j] = bf2f(qv[j]);
    float m = -INFINITY, l = 0.f;
    float acc[8];
#pragma unroll
    for (int j = 0; j < 8; j++) acc[j] = 0.f;
    const int e0 = offs[node], e1 = offs[node + 1];
    for (int e = e0; e < e1; ++e) {
        int s = ssrc[e];
        const u16x8 kv = *(const u16x8*)(QKVS + (size_t)s * QK4 + 512 + c0);
        const u16x8 vv = *(const u16x8*)(QKVS + (size_t)s * QK4 + 1024 + c0);
        float d = 0.f;
#pragma unroll
        for (int j = 0; j < 8; j++) d += qf[j] * bf2f(kv[j]);
        d += __shfl_xor(d, 1, 64);
        d += __shfl_xor(d, 2, 64);
        d += __shfl_xor(d, 4, 64);
        float a = d * 0.125f;
        float nm = fmaxf(m, a);
        float corr = __expf(m - nm);
        float p = __expf(a - nm);
        l = l * corr + p;
#pragma unroll
        for (int j = 0; j < 8; j++) acc[j] = acc[j] * corr + p * bf2f(vv[j]);
        m = nm;
    }
    float inv = 1.0f / (l + 1e-16f);
    const u16x8 sv = *(const u16x8*)(QKVS + (size_t)node * QK4 + 1536 + c0);
    u16x8 o;
#pragma unroll
    for (int j = 0; j < 8; j++) {
        float r = acc[j] * inv + bf2f(sv[j]);
        o[j] = f2bf(fmaxf(r, 0.f));
    }
    *(u16x8*)(Xout + (size_t)node * DDIM + c0) = o;
}

// ---------------- pooling ----------------
__global__ __launch_bounds__(256) void k_pool(const u16* __restrict__ X, float* __restrict__ pooled) {
    int t = threadIdx.x;
    int nd0 = blockIdx.x * 512;
    float s0 = 0.f, s1 = 0.f;
    for (int nd = nd0; nd < nd0 + 512; ++nd) {
        s0 += bf2f(X[(size_t)nd * DDIM + t]);
        s1 += bf2f(X[(size_t)nd * DDIM + 256 + t]);
    }
    atomicAdd(&pooled[t], s0);
    atomicAdd(&pooled[t + 256], s1);
}

// ---------------- heads: emb + hidden layers + critic ----------------
__global__ __launch_bounds__(1024) void k_heads(const float* __restrict__ pooled, const float* __restrict__ fcW,
                                                const float* __restrict__ fcb, const float* __restrict__ ui,
                                                const float* __restrict__ sp, const float* __restrict__ aW1,
                                                const float* __restrict__ ab1, const float* __restrict__ cW1,
                                                const float* __restrict__ cb1, const float* __restrict__ cW2,
                                                const float* __restrict__ cb2, float* __restrict__ hidden_a,
                                                float* __restrict__ out) {
    __shared__ float spool[512];
    __shared__ float semb[64];
    __shared__ float shc[8][128];
    int t = threadIdx.x;
    if (t < 512) spool[t] = pooled[t] * (1.0f / 32768.0f);
    __syncthreads();
    if (t < 64) {
        float s = fcb[t];
        for (int k = 0; k < 512; k++) s += spool[k] * fcW[k * 64 + t];
        semb[t] = s;
    }
    __syncthreads();
    int u = t >> 7, j = t & 127;
    float u0 = ui[u * 2], u1 = ui[u * 2 + 1], uspd = sp[u];
    float ha = ab1[j] + u0 * aW1[j] + u1 * aW1[128 + j] + uspd * aW1[66 * 128 + j];
    float hc = cb1[j] + u0 * cW1[j] + u1 * cW1[128 + j] + uspd * cW1[66 * 128 + j];
    for (int k = 0; k < 64; k++) {
        float e = semb[k];
        ha += e * aW1[(2 + k) * 128 + j];
        hc += e * cW1[(2 + k) * 128 + j];
    }
    ha = fmaxf(ha, 0.f);
    hc = fmaxf(hc, 0.f);
    hidden_a[u * 128 + j] = ha;
    shc[u][j] = hc;
    __syncthreads();
    if (t < 8) {
        float s = cb2[0];
        for (int k = 0; k < 128; k++) s += shc[t][k] * cW2[k];
        out[NNODES + t] = s;  // 8*4096 = 32768 probs first
    }
}

// ---------------- actor logits + softmax ----------------
__global__ __launch_bounds__(1024) void k_actor(const float* __restrict__ hidden_a, const float* __restrict__ aW2,
                                                const float* __restrict__ ab2, float* __restrict__ out) {
    __shared__ float h[128];
    __shared__ float red[1024];
    int u = blockIdx.x, t = threadIdx.x;
    if (t < 128) h[t] = hidden_a[u * 128 + t];
    __syncthreads();
    float lg[4];
#pragma unroll
    for (int p = 0; p < 4; p++) {
        int mcol = t + p * 1024;
        float s = ab2[mcol];
        for (int k = 0; k < 128; k++) s += h[k] * aW2[(size_t)k * MM + mcol];
        lg[p] = s;
    }
    float mx = fmaxf(fmaxf(lg[0], lg[1]), fmaxf(lg[2], lg[3]));
    red[t] = mx;
    __syncthreads();
    for (int s2 = 512; s2 > 0; s2 >>= 1) {
        if (t < s2) red[t] = fmaxf(red[t], red[t + s2]);
        __syncthreads();
    }
    mx = red[0];
    __syncthreads();
    float e[4], sum = 0.f;
#pragma unroll
    for (int p = 0; p < 4; p++) {
        e[p] = __expf(lg[p] - mx);
        sum += e[p];
    }
    red[t] = sum;
    __syncthreads();
    for (int s2 = 512; s2 > 0; s2 >>= 1) {
        if (t < s2) red[t] += red[t + s2];
        __syncthreads();
    }
    float inv = 1.0f / red[0];
#pragma unroll
    for (int p = 0; p < 4; p++) out[(size_t)u * MM + t + p * 1024] = e[p] * inv;
}

extern "C" void kernel_launch(void* const* d_in, const int* in_sizes, int n_in,
                              void* d_out, int out_size, void* d_ws, size_t ws_size,
                              hipStream_t stream) {
    const float* mc   = (const float*)d_in[0];
    const float* ui   = (const float*)d_in[1];
    const float* sp   = (const float*)d_in[2];
    const float* cm   = (const float*)d_in[3];
    const float* at   = (const float*)d_in[4];
    const int*   eidx = (const int*)d_in[5];
    const int*   mask = (const int*)d_in[7];
    const float* Wq0 = (const float*)d_in[8];
    const float* bq0 = (const float*)d_in[9];
    const float* Wk0 = (const float*)d_in[10];
    const float* bk0 = (const float*)d_in[11];
    const float* Wv0 = (const float*)d_in[12];
    const float* bv0 = (const float*)d_in[13];
    const float* Ws0 = (const float*)d_in[14];
    const float* bs0 = (const float*)d_in[15];
    const float* Wq = (const float*)d_in[16];
    const float* bq = (const float*)d_in[17];
    const float* Wk = (const float*)d_in[18];
    const float* bk = (const float*)d_in[19];
    const float* Wv = (const float*)d_in[20];
    const float* bv = (const float*)d_in[21];
    const float* Ws = (const float*)d_in[22];
    const float* bs = (const float*)d_in[23];
    const float* fcW = (const float*)d_in[24];
    const float* fcb = (const float*)d_in[25];
    const float* aW1 = (const float*)d_in[26];
    const float* ab1 = (const float*)d_in[27];
    const float* aW2 = (const float*)d_in[28];
    const float* ab2 = (const float*)d_in[29];
    const float* cW1 = (const float*)d_in[30];
    const float* cb1 = (const float*)d_in[31];
    const float* cW2 = (const float*)d_in[32];
    const float* cb2 = (const float*)d_in[33];
    float* out = (float*)d_out;

    const int* esrc = eidx;
    const int* edst = eidx + NEDGES;

    char* ws = (char*)d_ws;
    size_t off = 0;
    auto alloc = [&](size_t bytes) -> void* {
        void* p = ws + off;
        off += (bytes + 255) & ~(size_t)255;
        return p;
    };
    u16*   QKVS  = (u16*)alloc((size_t)NNODES * QK4 * 2);    // 128 MB
    u16*   X     = (u16*)alloc((size_t)NNODES * DDIM * 2);   // 32 MB
    u16*   Wt    = (u16*)alloc((size_t)3 * QK4 * DDIM * 2);  // 6 MB
    float* W0cat = (float*)alloc((size_t)6 * QK4 * 4);
    float* b0cat = (float*)alloc((size_t)QK4 * 4);
    float* bcat  = (float*)alloc((size_t)3 * QK4 * 4);
    float* x0    = (float*)alloc((size_t)NNODES * 6 * 4);
    int*   deg   = (int*)alloc((size_t)NNODES * 4);
    int*   offs  = (int*)alloc((size_t)(NNODES + 1) * 4);
    int*   cursor= (int*)alloc((size_t)NNODES * 4);
    int*   ssrc  = (int*)alloc((size_t)NEDGES * 4);
    float* pooled= (float*)alloc((size_t)512 * 4);
    float* hidden_a = (float*)alloc((size_t)UU * 128 * 4);
    (void)ws_size; (void)in_sizes; (void)n_in; (void)out_size;

    // prep
    k_zero<<<(NNODES + 255) / 256, 256, 0, stream>>>((unsigned int*)deg, NNODES);
    k_zero<<<2, 256, 0, stream>>>((unsigned int*)pooled, 512);
    k_build_x0<<<NNODES / 256, 256, 0, stream>>>(mc, mask, sp, cm, at, x0);
    k_w0cat<<<(6 * QK4 + 255) / 256, 256, 0, stream>>>(Wq0, Wk0, Wv0, Ws0, W0cat);
    k_bcat<<<(4 * QK4 + 255) / 256, 256, 0, stream>>>(bq0, bk0, bv0, bs0, bq, bk, bv, bs, b0cat, bcat);
    {
        dim3 g(16, 16, 12), b(32, 8);
        k_wt<<<g, b, 0, stream>>>(Wq, Wk, Wv, Ws, Wt);
    }
    // CSR
    k_count<<<NEDGES / 256, 256, 0, stream>>>(edst, deg);
    k_scan<<<1, 1024, 0, stream>>>(deg, offs, cursor);
    k_scatter<<<NEDGES / 256, 256, 0, stream>>>(esrc, edst, cursor, ssrc);

    // layer 0
    k_gemm0<<<NNODES, 256, 0, stream>>>(x0, W0cat, b0cat, QKVS);
    k_attn<<<NNODES / 4, 256, 0, stream>>>(QKVS, offs, ssrc, X);

    // layers 1..3
    for (int l = 0; l < 3; ++l) {
        k_gemm<<<4096, 256, 0, stream>>>(X, Wt + (size_t)l * QK4 * DDIM, bcat + (size_t)l * QK4, QKVS);
        k_attn<<<NNODES / 4, 256, 0, stream>>>(QKVS, offs, ssrc, X);
    }

    // pool + heads
    k_pool<<<64, 256, 0, stream>>>(X, pooled);
    k_heads<<<1, 1024, 0, stream>>>(pooled, fcW, fcb, ui, sp, aW1, ab1, cW1, cb1, cW2, cb2, hidden_a, out);
    k_actor<<<UU, 1024, 0, stream>>>(hidden_a, aW2, ab2, out);
}

// Round 4
// 660.713 us; speedup vs baseline: 1.1894x; 1.0791x over previous
//
#include <hip/hip_runtime.h>
#include <stdint.h>

typedef unsigned short u16;
typedef __attribute__((ext_vector_type(8))) unsigned short u16x8;
typedef __attribute__((ext_vector_type(8))) __bf16 bf16x8;
typedef __attribute__((ext_vector_type(4))) float f32x4;
typedef __attribute__((ext_vector_type(2))) float f32x2;

#define NNODES 32768
#define NEDGES 131072
#define DDIM 512
#define QK4 2048   // 4*DDIM
#define MM 4096
#define UU 8

__device__ __forceinline__ u16 f2bf(float f) {
    unsigned u = __builtin_bit_cast(unsigned, f);
    u += 0x7FFFu + ((u >> 16) & 1u);
    return (u16)(u >> 16);
}
__device__ __forceinline__ float bf2f(u16 h) {
    return __builtin_bit_cast(float, (unsigned)h << 16);
}

// pack 8 floats -> 8 fp8(e4m3) bytes (2x int32)
__device__ __forceinline__ void enc8(const float* f, int* lo, int* hi) {
    int a = __builtin_amdgcn_cvt_pk_fp8_f32(f[0], f[1], 0, false);
    a = __builtin_amdgcn_cvt_pk_fp8_f32(f[2], f[3], a, true);
    int b = __builtin_amdgcn_cvt_pk_fp8_f32(f[4], f[5], 0, false);
    b = __builtin_amdgcn_cvt_pk_fp8_f32(f[6], f[7], b, true);
    *lo = a;
    *hi = b;
}

__device__ __forceinline__ void load_lds16(const void* g, void* l) {
    __builtin_amdgcn_global_load_lds((__attribute__((address_space(1))) unsigned int*)(void*)g,
                                     (__attribute__((address_space(3))) unsigned int*)l, 16, 0, 0);
}

// ---------------- utility ----------------
__global__ void k_zero(unsigned int* p, int n) {
    int i = blockIdx.x * 256 + threadIdx.x;
    if (i < n) p[i] = 0u;
}

// ---------------- input prep ----------------
__global__ void k_build_x0(const float* __restrict__ mc, const int* __restrict__ mask,
                           const float* __restrict__ sp, const float* __restrict__ cm,
                           const float* __restrict__ at, float* __restrict__ x0) {
    int node = blockIdx.x * 256 + threadIdx.x;
    if (node >= NNODES) return;
    int m = node >> 3, u = node & 7;
    float* o = x0 + (size_t)node * 6;
    o[0] = mc[m * 2];
    o[1] = mc[m * 2 + 1];
    o[2] = (float)mask[m];
    o[3] = sp[u];
    o[4] = cm[u * MM + m];
    o[5] = at[u * MM + m];
}

__global__ void k_w0cat(const float* __restrict__ Wq0, const float* __restrict__ Wk0,
                        const float* __restrict__ Wv0, const float* __restrict__ Ws0,
                        float* __restrict__ W0cat) {
    int i = blockIdx.x * 256 + threadIdx.x;
    if (i >= 6 * QK4) return;
    int k = i / QK4, n = i % QK4;
    int t = n >> 9, nn = n & 511;
    const float* p = (t == 0) ? Wq0 : (t == 1) ? Wk0 : (t == 2) ? Wv0 : Ws0;
    W0cat[i] = p[k * DDIM + nn];
}

__global__ void k_bcat(const float* __restrict__ bq0, const float* __restrict__ bk0,
                       const float* __restrict__ bv0, const float* __restrict__ bs0,
                       const float* __restrict__ bq, const float* __restrict__ bk,
                       const float* __restrict__ bv, const float* __restrict__ bs,
                       float* __restrict__ b0cat, float* __restrict__ bcat) {
    int i = blockIdx.x * 256 + threadIdx.x;  // 0..8191
    if (i >= 4 * QK4) return;
    int n = i & (QK4 - 1);
    int l = i >> 11;
    int t = n >> 9, nn = n & 511;
    if (l == 0) {
        const float* p = (t == 0) ? bq0 : (t == 1) ? bk0 : (t == 2) ? bv0 : bs0;
        b0cat[n] = p[nn];
    } else {
        const float* p = (t == 0) ? bq : (t == 1) ? bk : (t == 2) ? bv : bs;
        bcat[(size_t)(l - 1) * QK4 + n] = p[(l - 1) * DDIM + nn];
    }
}

// transpose [512][512] fp32 matrices into Wt[layer][2048][512] bf16 ([n][k])
__global__ void k_wt(const float* __restrict__ Wq, const float* __restrict__ Wk,
                     const float* __restrict__ Wv, const float* __restrict__ Ws,
                     u16* __restrict__ Wt) {
    __shared__ float tile[32][33];
    int q = blockIdx.z;
    int l = q >> 2, t = q & 3;
    const float* src = ((t == 0) ? Wq : (t == 1) ? Wk : (t == 2) ? Wv : Ws) + (size_t)l * DDIM * DDIM;
    int k0 = blockIdx.x * 32, n0 = blockIdx.y * 32;
    int tx = threadIdx.x, ty = threadIdx.y;
#pragma unroll
    for (int r = 0; r < 4; r++) tile[ty + 8 * r][tx] = src[(size_t)(k0 + ty + 8 * r) * DDIM + n0 + tx];
    __syncthreads();
    u16* dst = Wt + (size_t)l * QK4 * DDIM + (size_t)t * DDIM * DDIM;
#pragma unroll
    for (int r = 0; r < 4; r++) {
        int n = n0 + ty + 8 * r;
        dst[(size_t)n * DDIM + k0 + tx] = f2bf(tile[tx][ty + 8 * r]);
    }
}

// ---------------- CSR build ----------------
__global__ void k_count(const int* __restrict__ dst, int* __restrict__ deg) {
    int e = blockIdx.x * 256 + threadIdx.x;
    if (e < NEDGES) atomicAdd(&deg[dst[e]], 1);
}

__global__ __launch_bounds__(1024) void k_scan(const int* __restrict__ deg, int* __restrict__ offs,
                                               int* __restrict__ cursor) {
    __shared__ int sums[1024];
    int t = threadIdx.x;
    int base = t * 32;
    int local[32];
    int s = 0;
#pragma unroll
    for (int i = 0; i < 32; i++) { local[i] = s; s += deg[base + i]; }
    sums[t] = s;
    __syncthreads();
    for (int d = 1; d < 1024; d <<= 1) {
        int v = (t >= d) ? sums[t - d] : 0;
        __syncthreads();
        sums[t] += v;
        __syncthreads();
    }
    int excl = (t == 0) ? 0 : sums[t - 1];
#pragma unroll
    for (int i = 0; i < 32; i++) {
        int o = excl + local[i];
        offs[base + i] = o;
        cursor[base + i] = o;
    }
    if (t == 1023) offs[NNODES] = sums[1023];
}

__global__ void k_scatter(const int* __restrict__ src, const int* __restrict__ dst,
                          int* __restrict__ cursor, int* __restrict__ ssrc) {
    int e = blockIdx.x * 256 + threadIdx.x;
    if (e < NEDGES) {
        int pos = atomicAdd(&cursor[dst[e]], 1);
        ssrc[pos] = src[e];
    }
}

// ---------------- layer 0 GEMM (K=6) ----------------
// writes Q,S as bf16 into QS[node][1024], K,V as fp8 into KV8[node][1024] (K/V interleaved per 8B chunk)
__global__ __launch_bounds__(256) void k_gemm0(const float* __restrict__ x0, const float* __restrict__ W0cat,
                                               const float* __restrict__ b0cat, u16* __restrict__ QS,
                                               unsigned char* __restrict__ KV8) {
    int node = blockIdx.x;
    int t = threadIdx.x;
    float xv[6];
#pragma unroll
    for (int k = 0; k < 6; k++) xv[k] = x0[(size_t)node * 6 + k];
    int n0 = t * 8;
    float f[8];
#pragma unroll
    for (int j = 0; j < 8; j++) {
        int n = n0 + j;
        float s = b0cat[n];
#pragma unroll
        for (int k = 0; k < 6; k++) s += xv[k] * W0cat[k * QK4 + n];
        f[j] = s;
    }
    if (n0 < 512) {
        u16x8 o;
#pragma unroll
        for (int j = 0; j < 8; j++) o[j] = f2bf(f[j]);
        *(u16x8*)(QS + (size_t)node * 1024 + n0) = o;
    } else if (n0 < 1536) {
        int lo, hi;
        enc8(f, &lo, &hi);
        int kvcol = (n0 < 1024) ? (n0 - 512) : (n0 - 1024);
        int ofs = (n0 < 1024) ? 0 : 8;
        *(int2*)(KV8 + (size_t)node * 1024 + (size_t)(kvcol >> 3) * 16 + ofs) = make_int2(lo, hi);
    } else {
        u16x8 o;
#pragma unroll
        for (int j = 0; j < 8; j++) o[j] = f2bf(f[j]);
        *(u16x8*)(QS + (size_t)node * 1024 + 512 + (n0 - 1536)) = o;
    }
}

// ---------------- main MFMA GEMM: X[32768,512]bf16 @ Wt[2048,512]bf16^T ----------------
// XCD-aware 1-D grid (validated R3: FETCH 134->48MB). Epilogue routes columns:
// tiles 0-3 -> QS bf16 (Q), 4-11 -> KV8 fp8 interleaved, 12-15 -> QS bf16 (S)
__global__ __launch_bounds__(256, 4) void k_gemm(const u16* __restrict__ X, const u16* __restrict__ Wt,
                                                 const float* __restrict__ bcat, u16* __restrict__ QS,
                                                 unsigned char* __restrict__ KV8) {
    __shared__ __align__(16) u16 smem[2 * 128 * 64];  // 32 KB: As | Bs, reused as epilogue staging
    u16* As = smem;
    u16* Bs = smem + 128 * 64;
    const int tid = threadIdx.x;
    const int lane = tid & 63;
    const int w = tid >> 6;
    const int wm = w & 1, wn = w >> 1;
    const int bid = blockIdx.x;
    const int xcd = bid & 7;
    const int s = bid >> 3;
    const size_t arow0 = (size_t)(xcd * 32 + (s >> 4)) * 128;
    const size_t brow0 = (size_t)(s & 15) * 128;
    const int bt = (int)(brow0 >> 7);  // 0..15 column-tile id (uniform per block)

    f32x4 acc[4][4];
#pragma unroll
    for (int i = 0; i < 4; i++)
#pragma unroll
        for (int j = 0; j < 4; j++) acc[i][j] = (f32x4){0.f, 0.f, 0.f, 0.f};

    const int la = lane & 7;
    const int quad = lane >> 4;
    const int lm = lane & 15;

    for (int kt = 0; kt < 8; ++kt) {
        const int k0 = kt * 64;
#pragma unroll
        for (int t = 0; t < 4; ++t) {
            int idx = (w * 4 + t) * 64 + lane;
            int m = idx >> 3;
            int c = la ^ (m & 7);
            const u16* ga = X + (arow0 + m) * DDIM + (k0 + c * 8);
            const u16* gb = Wt + (brow0 + m) * DDIM + (k0 + c * 8);
            load_lds16(ga, &As[(size_t)((w * 4 + t) * 64) * 8]);
            load_lds16(gb, &Bs[(size_t)((w * 4 + t) * 64) * 8]);
        }
        __syncthreads();
#pragma unroll
        for (int kk = 0; kk < 2; ++kk) {
            bf16x8 af[4], bfg[4];
            int c = kk * 4 + quad;
#pragma unroll
            for (int i = 0; i < 4; ++i) {
                int m = wm * 64 + i * 16 + lm;
                int slot = m * 8 + (c ^ (m & 7));
                af[i] = *(const bf16x8*)&As[(size_t)slot * 8];
            }
#pragma unroll
            for (int j = 0; j < 4; ++j) {
                int n = wn * 64 + j * 16 + lm;
                int slot = n * 8 + (c ^ (n & 7));
                bfg[j] = *(const bf16x8*)&Bs[(size_t)slot * 8];
            }
#pragma unroll
            for (int i = 0; i < 4; ++i)
#pragma unroll
                for (int j = 0; j < 4; ++j)
                    acc[i][j] = __builtin_amdgcn_mfma_f32_16x16x32_bf16(af[i], bfg[j], acc[i][j], 0, 0, 0);
        }
        __syncthreads();
    }

    // epilogue: stage wave's 64x64 subtile through LDS -> coalesced readback, route by bt
    float biasv[4];
#pragma unroll
    for (int j = 0; j < 4; ++j) biasv[j] = bcat[brow0 + wn * 64 + j * 16 + lm];

    u16* stg = smem;  // [4 waves][32 rows][72 u16]
    const int chunk = lane & 7;
    const int rrow = lane >> 3;
    const int colbase = (int)brow0 + wn * 64 + chunk * 8;  // global col of this lane's 8 cols
#pragma unroll
    for (int p = 0; p < 2; ++p) {
        __syncthreads();
#pragma unroll
        for (int ii = 0; ii < 2; ++ii) {
            int i = p * 2 + ii;
#pragma unroll
            for (int j = 0; j < 4; ++j) {
#pragma unroll
                for (int r = 0; r < 4; ++r) {
                    int lr = ii * 16 + quad * 4 + r;
                    int lc = j * 16 + lm;
                    stg[(size_t)(w * 32 + lr) * 72 + lc] = f2bf(acc[i][j][r] + biasv[j]);
                }
            }
        }
        __syncthreads();
#pragma unroll
        for (int it = 0; it < 4; ++it) {
            int row = it * 8 + rrow;
            u16x8 v = *(const u16x8*)&stg[(size_t)(w * 32 + row) * 72 + chunk * 8];
            size_t grow = arow0 + wm * 64 + p * 32 + row;
            if (bt < 4) {
                *(u16x8*)&QS[grow * 1024 + colbase] = v;
            } else if (bt < 12) {
                float f[8];
#pragma unroll
                for (int j = 0; j < 8; j++) f[j] = bf2f(v[j]);
                int lo, hi;
                enc8(f, &lo, &hi);
                int kvcol = (bt < 8) ? (colbase - 512) : (colbase - 1024);
                int ofs = (bt < 8) ? 0 : 8;
                *(int2*)(KV8 + grow * 1024 + (size_t)(kvcol >> 3) * 16 + ofs) = make_int2(lo, hi);
            } else {
                *(u16x8*)&QS[grow * 1024 + 512 + (colbase - 1536)] = v;
            }
        }
    }
}

// ---------------- attention: one wave per dst node, fp8 K/V gathers ----------------
__global__ __launch_bounds__(256) void k_attn(const u16* __restrict__ QS, const unsigned char* __restrict__ KV8,
                                              const int* __restrict__ offs, const int* __restrict__ ssrc,
                                              u16* __restrict__ Xout) {
    const int lane = threadIdx.x & 63;
    const int node = blockIdx.x * 4 + (threadIdx.x >> 6);
    const int c0 = lane * 8;
    const u16x8 qv = *(const u16x8*)(QS + (size_t)node * 1024 + c0);
    float qf[8];
#pragma unroll
    for (int j = 0; j < 8; j++) qf[j] = bf2f(qv[j]);
    float m = -INFINITY, l = 0.f;
    float acc[8];
#pragma unroll
    for (int j = 0; j < 8; j++) acc[j] = 0.f;
    const int e0 = offs[node], e1 = offs[node + 1];
    for (int e = e0; e < e1; ++e) {
        int s = ssrc[e];
        int4 kv = *(const int4*)(KV8 + (size_t)s * 1024 + (size_t)lane * 16);
        f32x2 k01 = __builtin_amdgcn_cvt_pk_f32_fp8(kv.x, false);
        f32x2 k23 = __builtin_amdgcn_cvt_pk_f32_fp8(kv.x, true);
        f32x2 k45 = __builtin_amdgcn_cvt_pk_f32_fp8(kv.y, false);
        f32x2 k67 = __builtin_amdgcn_cvt_pk_f32_fp8(kv.y, true);
        float d = qf[0] * k01[0] + qf[1] * k01[1] + qf[2] * k23[0] + qf[3] * k23[1] +
                  qf[4] * k45[0] + qf[5] * k45[1] + qf[6] * k67[0] + qf[7] * k67[1];
        d += __shfl_xor(d, 1, 64);
        d += __shfl_xor(d, 2, 64);
        d += __shfl_xor(d, 4, 64);
        float a = d * 0.125f;
        float nm = fmaxf(m, a);
        float corr = __expf(m - nm);
        float p = __expf(a - nm);
        l = l * corr + p;
        f32x2 v01 = __builtin_amdgcn_cvt_pk_f32_fp8(kv.z, false);
        f32x2 v23 = __builtin_amdgcn_cvt_pk_f32_fp8(kv.z, true);
        f32x2 v45 = __builtin_amdgcn_cvt_pk_f32_fp8(kv.w, false);
        f32x2 v67 = __builtin_amdgcn_cvt_pk_f32_fp8(kv.w, true);
        acc[0] = acc[0] * corr + p * v01[0];
        acc[1] = acc[1] * corr + p * v01[1];
        acc[2] = acc[2] * corr + p * v23[0];
        acc[3] = acc[3] * corr + p * v23[1];
        acc[4] = acc[4] * corr + p * v45[0];
        acc[5] = acc[5] * corr + p * v45[1];
        acc[6] = acc[6] * corr + p * v67[0];
        acc[7] = acc[7] * corr + p * v67[1];
        m = nm;
    }
    float inv = 1.0f / (l + 1e-16f);
    const u16x8 sv = *(const u16x8*)(QS + (size_t)node * 1024 + 512 + c0);
    u16x8 o;
#pragma unroll
    for (int j = 0; j < 8; j++) {
        float r = acc[j] * inv + bf2f(sv[j]);
        o[j] = f2bf(fmaxf(r, 0.f));
    }
    *(u16x8*)(Xout + (size_t)node * DDIM + c0) = o;
}

// ---------------- pooling (vectorized) ----------------
__global__ __launch_bounds__(256) void k_pool(const u16* __restrict__ X, float* __restrict__ pooled) {
    __shared__ float red[4][64][8];
    int t = threadIdx.x;
    int chunk = t & 63;
    int rofs = t >> 6;
    float s[8];
#pragma unroll
    for (int j = 0; j < 8; j++) s[j] = 0.f;
    int nd0 = blockIdx.x * 256;
    for (int nd = nd0 + rofs; nd < nd0 + 256; nd += 4) {
        u16x8 v = *(const u16x8*)&X[(size_t)nd * DDIM + chunk * 8];
#pragma unroll
        for (int j = 0; j < 8; j++) s[j] += bf2f(v[j]);
    }
#pragma unroll
    for (int j = 0; j < 8; j++) red[rofs][chunk][j] = s[j];
    __syncthreads();
    if (t < 64) {
#pragma unroll
        for (int j = 0; j < 8; j++) {
            float o = red[0][t][j] + red[1][t][j] + red[2][t][j] + red[3][t][j];
            atomicAdd(&pooled[t * 8 + j], o);
        }
    }
}

// ---------------- heads: emb + hidden layers + critic ----------------
__global__ __launch_bounds__(1024) void k_heads(const float* __restrict__ pooled, const float* __restrict__ fcW,
                                                const float* __restrict__ fcb, const float* __restrict__ ui,
                                                const float* __restrict__ sp, const float* __restrict__ aW1,
                                                const float* __restrict__ ab1, const float* __restrict__ cW1,
                                                const float* __restrict__ cb1, const float* __restrict__ cW2,
                                                const float* __restrict__ cb2, float* __restrict__ hidden_a,
                                                float* __restrict__ out) {
    __shared__ float spool[512];
    __shared__ float semb[64];
    __shared__ float shc[8][128];
    int t = threadIdx.x;
    if (t < 512) spool[t] = pooled[t] * (1.0f / 32768.0f);
    __syncthreads();
    if (t < 64) {
        float s = fcb[t];
        for (int k = 0; k < 512; k++) s += spool[k] * fcW[k * 64 + t];
        semb[t] = s;
    }
    __syncthreads();
    int u = t >> 7, j = t & 127;
    float u0 = ui[u * 2], u1 = ui[u * 2 + 1], uspd = sp[u];
    float ha = ab1[j] + u0 * aW1[j] + u1 * aW1[128 + j] + uspd * aW1[66 * 128 + j];
    float hc = cb1[j] + u0 * cW1[j] + u1 * cW1[128 + j] + uspd * cW1[66 * 128 + j];
    for (int k = 0; k < 64; k++) {
        float e = semb[k];
        ha += e * aW1[(2 + k) * 128 + j];
        hc += e * cW1[(2 + k) * 128 + j];
    }
    ha = fmaxf(ha, 0.f);
    hc = fmaxf(hc, 0.f);
    hidden_a[u * 128 + j] = ha;
    shc[u][j] = hc;
    __syncthreads();
    if (t < 8) {
        float s = cb2[0];
        for (int k = 0; k < 128; k++) s += shc[t][k] * cW2[k];
        out[NNODES + t] = s;
    }
}

// ---------------- actor logits + softmax ----------------
__global__ __launch_bounds__(1024) void k_actor(const float* __restrict__ hidden_a, const float* __restrict__ aW2,
                                                const float* __restrict__ ab2, float* __restrict__ out) {
    __shared__ float h[128];
    __shared__ float red[1024];
    int u = blockIdx.x, t = threadIdx.x;
    if (t < 128) h[t] = hidden_a[u * 128 + t];
    __syncthreads();
    float lg[4];
#pragma unroll
    for (int p = 0; p < 4; p++) {
        int mcol = t + p * 1024;
        float s = ab2[mcol];
        for (int k = 0; k < 128; k++) s += h[k] * aW2[(size_t)k * MM + mcol];
        lg[p] = s;
    }
    float mx = fmaxf(fmaxf(lg[0], lg[1]), fmaxf(lg[2], lg[3]));
    red[t] = mx;
    __syncthreads();
    for (int s2 = 512; s2 > 0; s2 >>= 1) {
        if (t < s2) red[t] = fmaxf(red[t], red[t + s2]);
        __syncthreads();
    }
    mx = red[0];
    __syncthreads();
    float e[4], sum = 0.f;
#pragma unroll
    for (int p = 0; p < 4; p++) {
        e[p] = __expf(lg[p] - mx);
        sum += e[p];
    }
    red[t] = sum;
    __syncthreads();
    for (int s2 = 512; s2 > 0; s2 >>= 1) {
        if (t < s2) red[t] += red[t + s2];
        __syncthreads();
    }
    float inv = 1.0f / red[0];
#pragma unroll
    for (int p = 0; p < 4; p++) out[(size_t)u * MM + t + p * 1024] = e[p] * inv;
}

extern "C" void kernel_launch(void* const* d_in, const int* in_sizes, int n_in,
                              void* d_out, int out_size, void* d_ws, size_t ws_size,
                              hipStream_t stream) {
    const float* mc   = (const float*)d_in[0];
    const float* ui   = (const float*)d_in[1];
    const float* sp   = (const float*)d_in[2];
    const float* cm   = (const float*)d_in[3];
    const float* at   = (const float*)d_in[4];
    const int*   eidx = (const int*)d_in[5];
    const int*   mask = (const int*)d_in[7];
    const float* Wq0 = (const float*)d_in[8];
    const float* bq0 = (const float*)d_in[9];
    const float* Wk0 = (const float*)d_in[10];
    const float* bk0 = (const float*)d_in[11];
    const float* Wv0 = (const float*)d_in[12];
    const float* bv0 = (const float*)d_in[13];
    const float* Ws0 = (const float*)d_in[14];
    const float* bs0 = (const float*)d_in[15];
    const float* Wq = (const float*)d_in[16];
    const float* bq = (const float*)d_in[17];
    const float* Wk = (const float*)d_in[18];
    const float* bk = (const float*)d_in[19];
    const float* Wv = (const float*)d_in[20];
    const float* bv = (const float*)d_in[21];
    const float* Ws = (const float*)d_in[22];
    const float* bs = (const float*)d_in[23];
    const float* fcW = (const float*)d_in[24];
    const float* fcb = (const float*)d_in[25];
    const float* aW1 = (const float*)d_in[26];
    const float* ab1 = (const float*)d_in[27];
    const float* aW2 = (const float*)d_in[28];
    const float* ab2 = (const float*)d_in[29];
    const float* cW1 = (const float*)d_in[30];
    const float* cb1 = (const float*)d_in[31];
    const float* cW2 = (const float*)d_in[32];
    const float* cb2 = (const float*)d_in[33];
    float* out = (float*)d_out;

    const int* esrc = eidx;
    const int* edst = eidx + NEDGES;

    char* ws = (char*)d_ws;
    size_t off = 0;
    auto alloc = [&](size_t bytes) -> void* {
        void* p = ws + off;
        off += (bytes + 255) & ~(size_t)255;
        return p;
    };
    u16*   QS    = (u16*)alloc((size_t)NNODES * 1024 * 2);           // 64 MB (Q|S bf16)
    unsigned char* KV8 = (unsigned char*)alloc((size_t)NNODES * 1024); // 32 MB (K|V fp8 interleaved)
    u16*   X     = (u16*)alloc((size_t)NNODES * DDIM * 2);           // 32 MB
    u16*   Wt    = (u16*)alloc((size_t)3 * QK4 * DDIM * 2);          // 6 MB
    float* W0cat = (float*)alloc((size_t)6 * QK4 * 4);
    float* b0cat = (float*)alloc((size_t)QK4 * 4);
    float* bcat  = (float*)alloc((size_t)3 * QK4 * 4);
    float* x0    = (float*)alloc((size_t)NNODES * 6 * 4);
    int*   deg   = (int*)alloc((size_t)NNODES * 4);
    int*   offs  = (int*)alloc((size_t)(NNODES + 1) * 4);
    int*   cursor= (int*)alloc((size_t)NNODES * 4);
    int*   ssrc  = (int*)alloc((size_t)NEDGES * 4);
    float* pooled= (float*)alloc((size_t)512 * 4);
    float* hidden_a = (float*)alloc((size_t)UU * 128 * 4);
    (void)ws_size; (void)in_sizes; (void)n_in; (void)out_size;

    // prep
    k_zero<<<(NNODES + 255) / 256, 256, 0, stream>>>((unsigned int*)deg, NNODES);
    k_zero<<<2, 256, 0, stream>>>((unsigned int*)pooled, 512);
    k_build_x0<<<NNODES / 256, 256, 0, stream>>>(mc, mask, sp, cm, at, x0);
    k_w0cat<<<(6 * QK4 + 255) / 256, 256, 0, stream>>>(Wq0, Wk0, Wv0, Ws0, W0cat);
    k_bcat<<<(4 * QK4 + 255) / 256, 256, 0, stream>>>(bq0, bk0, bv0, bs0, bq, bk, bv, bs, b0cat, bcat);
    {
        dim3 g(16, 16, 12), b(32, 8);
        k_wt<<<g, b, 0, stream>>>(Wq, Wk, Wv, Ws, Wt);
    }
    // CSR
    k_count<<<NEDGES / 256, 256, 0, stream>>>(edst, deg);
    k_scan<<<1, 1024, 0, stream>>>(deg, offs, cursor);
    k_scatter<<<NEDGES / 256, 256, 0, stream>>>(esrc, edst, cursor, ssrc);

    // layer 0
    k_gemm0<<<NNODES, 256, 0, stream>>>(x0, W0cat, b0cat, QS, KV8);
    k_attn<<<NNODES / 4, 256, 0, stream>>>(QS, KV8, offs, ssrc, X);

    // layers 1..3
    for (int l = 0; l < 3; ++l) {
        k_gemm<<<4096, 256, 0, stream>>>(X, Wt + (size_t)l * QK4 * DDIM, bcat + (size_t)l * QK4, QS, KV8);
        k_attn<<<NNODES / 4, 256, 0, stream>>>(QS, KV8, offs, ssrc, X);
    }

    // pool + heads
    k_pool<<<128, 256, 0, stream>>>(X, pooled);
    k_heads<<<1, 1024, 0, stream>>>(pooled, fcW, fcb, ui, sp, aW1, ab1, cW1, cb1, cW2, cb2, hidden_a, out);
    k_actor<<<UU, 1024, 0, stream>>>(hidden_a, aW2, ab2, out);
}